// Round 18
// baseline (624.485 us; speedup 1.0000x reference)
//
#include <hip/hip_runtime.h>

// SubsetGFlowNetTB: 17-step GFlowNet trajectory-balance forward.
// R18 = 1-step chunks -> 5 blocks/CU (20 waves): h = one step's rows
// (16.9KB), total LDS 23.9KB, launch_bounds(256,5) (102-reg budget).
// Phase C: 2 passes x (2pt x 1rt) = 32 acc regs (R16's spill shape avoided
// structurally) with one h2-fragment read serving 2 MFMAs (C ds_reads halve).
// Patch-mask logic gone (selw commits between steps). Cost: full A recompute
// per step, 4 barriers/step -- paid by +25% resident waves.

#define NEG_INF (-1000000000.0f)
#define LOG2E 1.4426950408889634f
#define LN2   0.6931471805599453f

// amask ushort: [9:0] action (1023 = dead), [10] new, [15:11] kcnt (k>=16 <=> bit15)
#define A_NEW  0x400

// h LDS layout constants (1-step: 32 rows + 1 pad row per ktg block)
#define HST 528             // bytes per ktg block (33 rows * 16B)
#define HKT 1056            // kt stride = 2*HST

typedef short bf16x8 __attribute__((ext_vector_type(8)));
typedef float f32x16 __attribute__((ext_vector_type(16)));

__device__ __forceinline__ unsigned short f2bf(float x){
  unsigned int u = __float_as_uint(x);
  u = (u + 0x7FFFu + ((u >> 16) & 1u)) >> 16;   // RNE
  return (unsigned short)u;
}
__device__ __forceinline__ float bf2f(unsigned short h){
  return __uint_as_float(((unsigned int)h) << 16);
}
__device__ __forceinline__ unsigned int cvt_pk_bf16(float lo, float hi){
  unsigned int r;
  asm("v_cvt_pk_bf16_f32 %0, %1, %2" : "=v"(r) : "v"(lo), "v"(hi));
  return r;
}
__device__ __forceinline__ float4 ld4bf(const unsigned short* p){
  ushort4 u = *(const ushort4*)p;
  return make_float4(bf2f(u.x), bf2f(u.y), bf2f(u.z), bf2f(u.w));
}

// ---------------------------------------------------------------------------
// Prep: W2 (256x256 f32), Wh (256x513 f32) -> bf16 MFMA fragments.
// Layout: fragment tile index = ntg*16 + kt (kt fastest, 1024B kt-stride).
// Lane l of tile (ntg,kt) holds M[kt*16+(l>>5)*8+i][ntg*32+(l&31)].
// whf PRE-SCALED by log2(e).
// ---------------------------------------------------------------------------
__global__ void prep_kernel(const float* __restrict__ W2, const float* __restrict__ Wh,
                            unsigned short* __restrict__ w2f, unsigned short* __restrict__ whf,
                            float* __restrict__ whstop){
  int id = blockIdx.x * 256 + threadIdx.x;
  if (id < 8192){                       // W2 fragments: tile = ntg*16 + kt
    int lane = id & 63; int tile = id >> 6;
    int ntg = tile >> 4, kt = tile & 15;
    int col = ntg * 32 + (lane & 31);
    int k0  = kt * 16 + (lane >> 5) * 8;
    unsigned int u[4];
#pragma unroll
    for (int p = 0; p < 4; ++p){
      unsigned short lo = f2bf(W2[(k0 + 2*p    ) * 256 + col]);
      unsigned short hi = f2bf(W2[(k0 + 2*p + 1) * 256 + col]);
      u[p] = (unsigned int)lo | ((unsigned int)hi << 16);
    }
    *(uint4*)(w2f + (size_t)id * 8) = make_uint4(u[0], u[1], u[2], u[3]);
  } else if (id < 24576){               // Wh fragments: tile = pt*16 + kt, x log2e
    int id2 = id - 8192;
    int lane = id2 & 63; int tile = id2 >> 6;
    int pt = tile >> 4, kt = tile & 15;
    int col = pt * 32 + (lane & 31);
    int k0  = kt * 16 + (lane >> 5) * 8;
    unsigned int u[4];
#pragma unroll
    for (int p = 0; p < 4; ++p){
      unsigned short lo = f2bf(Wh[(k0 + 2*p    ) * 513 + col] * LOG2E);
      unsigned short hi = f2bf(Wh[(k0 + 2*p + 1) * 513 + col] * LOG2E);
      u[p] = (unsigned int)lo | ((unsigned int)hi << 16);
    }
    *(uint4*)(whf + (size_t)id2 * 8) = make_uint4(u[0], u[1], u[2], u[3]);
  } else if (id < 24832){               // stop column, f32, unscaled
    int k = id - 24576;
    whstop[k] = Wh[k * 513 + 512];
  }
}

// ---------------------------------------------------------------------------
// Fused kernel: 256 threads (4 waves) own 32 samples, 17 single-step chunks.
// h in fragment-native layout h[32 ktg][33-row-pad][8 shorts] (h1 then h2).
// ---------------------------------------------------------------------------
__launch_bounds__(256, 5)
__global__ void gfn_kernel(const int* __restrict__ actions, const float* __restrict__ rp,
                           const float* __restrict__ W1, const float* __restrict__ b1,
                           const float* __restrict__ b2, const float* __restrict__ bh,
                           const unsigned short* __restrict__ w2f,
                           const unsigned short* __restrict__ whf,
                           const float* __restrict__ whstop,
                           float* __restrict__ out)
{
  __shared__ alignas(16) char h[32 * HST];              // 16896 (h1, then h2)
  __shared__ alignas(16) unsigned short c16[1024];      // 2048: ck/ct/cr/cb bf16
  __shared__ alignas(16) float bhl2[512];               // 2048: bh*log2e f32 frag order
  __shared__ alignas(16) float b2s[256];                // 1024 f32
  __shared__ alignas(16) unsigned short whst_h[256];    // 512 stop col bf16
  __shared__ alignas(16) unsigned short amask[17][32];  // 1088
  __shared__ alignas(16) float predsum[32];             // 128 softmax partials
  __shared__ alignas(16) float stopp[32];               // 128 stop partials
  __shared__ alignas(16) unsigned short chosen16[32];   // 64  => ~23.9 KB

  const int tid  = threadIdx.x;
  const int wave = tid >> 6;            // 0..3
  const int lane = tid & 63;
  const int ln5  = lane & 31;
  const int lg2  = lane >> 5;
  const int base = blockIdx.x * 32;

  // ---- init ----
  for (int i = tid; i < 1024; i += 256){
    int rrow = i >> 8, f = i & 255;
    float v = (rrow < 3) ? W1[(512 + rrow) * 256 + f] : b1[f];
    c16[i] = f2bf(v);
  }
  b2s[tid] = b2[tid];
  whst_h[tid] = f2bf(whstop[tid]);
  for (int i = tid; i < 512; i += 256){
    int pt = i >> 5, l2 = (i >> 4) & 1, r = i & 15;
    int col = pt * 32 + (r & 3) + 8 * (r >> 2) + 4 * l2;
    bhl2[i] = bh[col] * LOG2E;
  }
  const float stopbias = bh[512];
  if (tid < 32){ stopp[tid] = 0.f; predsum[tid] = 0.f; }
  int* acts = (int*)h;                  // stage actions in h scratch
  for (int i = tid; i < 544; i += 256) acts[i] = actions[base * 17 + i];
  float logpf = 0.f;                    // valid for tid<32 (sample tid)
  // selection mask in registers: wave w owns pt-words w*4..w*4+3 for its
  // sample ln5 (maintained redundantly by both half-waves)
  uint4 selw_r = make_uint4(0u, 0u, 0u, 0u);
  __syncthreads();

  // ---- state precompute: O(17^2) scan per sample; no GEMM dependency ----
  if (tid < 32){
    int s = tid, k = 0;
    for (int t = 0; t < 17; ++t){
      int a = acts[s * 17 + t];
      bool alive = (a >= 0);
      bool isnew = alive && (a < 512);
      if (isnew){
        for (int u = 0; u < t; ++u) if (acts[s * 17 + u] == a){ isnew = false; break; }
      }
      int av = alive ? a : 1023;
      amask[t][s] = (unsigned short)(av | (isnew ? A_NEW : 0) | (k << 11));
      if (isnew) ++k;
    }
  }
  // packed layer-1 running sum: Spk[2*s8+{0,1}] = bf16x2 of feats {0,1},{2,3}
  unsigned int Spk[16];
#pragma unroll
  for (int j = 0; j < 16; ++j) Spk[j] = 0u;
  __syncthreads();

  // fragment-layout base addresses (all loop-invariant, 32-bit)
  const int aw_base = (lane >> 1) * HST + (lane & 1) * 8 + wave * 128; // A writes (+s8*16)
  const int br_base = lg2 * HST + ln5 * 16;                           // B reads (+kt*HKT)
  const int bw_base = wave * 8 * HST + lg2 * 8 + ln5 * 16;            // B writes (+g*HST)
  const int cr_base = lg2 * HST + ln5 * 16;                           // C reads (+kt*HKT)
  const int rpu = __builtin_amdgcn_readfirstlane(base + wave * 8);    // uniform rp index
  // weight-fragment per-lane bases (32-bit offsets; kt-stride 512 shorts)
  const unsigned lane8 = (unsigned)lane * 8u;
  const unsigned short* w2p0 = w2f + (unsigned)(wave * 2    ) * 8192u + lane8;
  const unsigned short* w2p1 = w2f + (unsigned)(wave * 2 + 1) * 8192u + lane8;

#pragma unroll 1
  for (int t = 0; t < 17; ++t){

    // ---- deferred finalize of previous step (tid<32; overlaps A on others;
    //      resets complete before this step's B/C atomics, which are
    //      barrier-ordered after A) ----
    if (t > 0 && tid < 32){
      int s = tid;
      int m = amask[t - 1][s];
      int av = m & 1023;
      int k = m >> 11;
      float stop = (k == 0) ? NEG_INF : stopp[s] + stopbias;
      float tot = __expf(stop) + predsum[s];
      float lse = __logf(tot);
      if (av != 1023){
        float ch;
        if (av == 512) ch = stop;
        else {
          bool mskd = !(m & A_NEW) || (k >= 16);
          ch = mskd ? NEG_INF : bf2f(chosen16[s]) * LN2;
        }
        logpf += ch - lse;
      }
      stopp[s] = 0.f; predsum[s] = 0.f;
    }

    // ---- Phase A: h1 for step t; thread = (4 feats, 8 samples) ----
    {
      const float4 ck4 = ld4bf(&c16[lane * 4]);
      const float4 ct4 = ld4bf(&c16[256 + lane * 4]);
      const float4 cr4 = ld4bf(&c16[512 + lane * 4]);
      const float4 cb4 = ld4bf(&c16[768 + lane * 4]);
      float tf = (float)t;
      float c00 = cb4.x + tf * ct4.x, c01 = cb4.y + tf * ct4.y;
      float c02 = cb4.z + tf * ct4.z, c03 = cb4.w + tf * ct4.w;
#pragma unroll
      for (int s8 = 0; s8 < 8; ++s8){
        int s = wave * 8 + s8;
        float rv = rp[rpu + s8];                 // scalar load
        int m0 = amask[t][s];
        unsigned int pk0 = Spk[s8 * 2], pk1 = Spk[s8 * 2 + 1];
        float S0 = __uint_as_float(pk0 << 16);
        float S1 = __uint_as_float(pk0 & 0xFFFF0000u);
        float S2 = __uint_as_float(pk1 << 16);
        float S3 = __uint_as_float(pk1 & 0xFFFF0000u);
        float kf = (float)(m0 >> 11);
        float v0 = S0 + kf * ck4.x + rv * cr4.x + c00;
        float v1 = S1 + kf * ck4.y + rv * cr4.y + c01;
        float v2 = S2 + kf * ck4.z + rv * cr4.z + c02;
        float v3 = S3 + kf * ck4.w + rv * cr4.w + c03;
        *(uint2*)(h + aw_base + s8 * 16) =
            make_uint2(cvt_pk_bf16(fmaxf(v0,0.f), fmaxf(v1,0.f)),
                       cvt_pk_bf16(fmaxf(v2,0.f), fmaxf(v3,0.f)));
        if (m0 & A_NEW){                          // wave-uniform branch
          int a = m0 & 1023;
          float4 w = *(const float4*)(W1 + (size_t)a * 256 + lane * 4);
          S0 += w.x; S1 += w.y; S2 += w.z; S3 += w.w;
          Spk[s8 * 2]     = cvt_pk_bf16(S0, S1);
          Spk[s8 * 2 + 1] = cvt_pk_bf16(S2, S3);
        }
      }
    }
    __syncthreads();

    // ---- Phase B (swapped): D'[feat][row], single pass (32 rows). ----
    {
      f32x16 aB0, aB1;
#pragma unroll
      for (int i = 0; i < 16; ++i){ aB0[i] = 0.f; aB1[i] = 0.f; }
#pragma unroll 4
      for (int kt = 0; kt < 16; ++kt){
        bf16x8 sf = *(const bf16x8*)(h + br_base + kt * HKT);
        bf16x8 w0 = *(const bf16x8*)(w2p0 + (unsigned)(kt * 512));
        bf16x8 w1 = *(const bf16x8*)(w2p1 + (unsigned)(kt * 512));
        aB0 = __builtin_amdgcn_mfma_f32_32x32x16_bf16(w0, sf, aB0, 0, 0, 0);
        aB1 = __builtin_amdgcn_mfma_f32_32x32x16_bf16(w1, sf, aB1, 0, 0, 0);
      }
      __syncthreads();   // all waves done reading h1
      float sp = 0.f;
#pragma unroll
      for (int g = 0; g < 4; ++g){
        int f0 = wave * 64 + g * 8 + lg2 * 4;
        int f1 = f0 + 32;
        float4 bb0 = *(const float4*)&b2s[f0];
        float4 bb1 = *(const float4*)&b2s[f1];
        float4 ws0 = ld4bf(&whst_h[f0]);
        float4 ws1 = ld4bf(&whst_h[f1]);
        {
          float v0 = fmaxf(aB0[g*4+0] + bb0.x, 0.f), v1 = fmaxf(aB0[g*4+1] + bb0.y, 0.f);
          float v2 = fmaxf(aB0[g*4+2] + bb0.z, 0.f), v3 = fmaxf(aB0[g*4+3] + bb0.w, 0.f);
          sp += v0 * ws0.x + v1 * ws0.y + v2 * ws0.z + v3 * ws0.w;
          *(uint2*)(h + bw_base + g * HST) = make_uint2(cvt_pk_bf16(v0, v1), cvt_pk_bf16(v2, v3));
        }
        {
          float v0 = fmaxf(aB1[g*4+0] + bb1.x, 0.f), v1 = fmaxf(aB1[g*4+1] + bb1.y, 0.f);
          float v2 = fmaxf(aB1[g*4+2] + bb1.z, 0.f), v3 = fmaxf(aB1[g*4+3] + bb1.w, 0.f);
          sp += v0 * ws1.x + v1 * ws1.y + v2 * ws1.z + v3 * ws1.w;
          *(uint2*)(h + bw_base + (g + 4) * HST) = make_uint2(cvt_pk_bf16(v0, v1), cvt_pk_bf16(v2, v3));
        }
      }
      sp += __shfl_xor(sp, 32);
      if (lg2 == 0) atomicAdd(&stopp[ln5], sp);
    }
    __syncthreads();   // h2 fully written

    // ---- Phase C (swapped): lane owns sample ln5; 2 passes of 2 pt accs
    //      sharing one h2-fragment read; acc init = bias*log2e. ----
    {
      int mt = amask[t][ln5];
      int av = mt & 1023;
      float sum = 0.f;
#pragma unroll 1
      for (int pp = 0; pp < 2; ++pp){
        int pt0 = wave * 4 + pp * 2;
        int pt1 = pt0 + 1;
        const unsigned short* wp0 = whf + (unsigned)pt0 * 8192u + lane8;
        const unsigned short* wp1 = wp0 + 8192u;
        f32x16 a0, a1;
        {
          const float* bi0 = &bhl2[pt0 * 32 + lg2 * 16];
          const float* bi1 = &bhl2[pt1 * 32 + lg2 * 16];
#pragma unroll
          for (int g = 0; g < 4; ++g){
            float4 u0 = *(const float4*)(bi0 + g * 4);
            float4 u1 = *(const float4*)(bi1 + g * 4);
            a0[g*4+0]=u0.x; a0[g*4+1]=u0.y; a0[g*4+2]=u0.z; a0[g*4+3]=u0.w;
            a1[g*4+0]=u1.x; a1[g*4+1]=u1.y; a1[g*4+2]=u1.z; a1[g*4+3]=u1.w;
          }
        }
#pragma unroll 4
        for (int kt = 0; kt < 16; ++kt){
          bf16x8 f0 = *(const bf16x8*)(h + cr_base + kt * HKT);
          bf16x8 w0 = *(const bf16x8*)(wp0 + (unsigned)(kt * 512));
          bf16x8 w1 = *(const bf16x8*)(wp1 + (unsigned)(kt * 512));
          a0 = __builtin_amdgcn_mfma_f32_32x32x16_bf16(w0, f0, a0, 0, 0, 0);
          a1 = __builtin_amdgcn_mfma_f32_32x32x16_bf16(w1, f0, a1, 0, 0, 0);
        }
        unsigned word0 = pp ? selw_r.z : selw_r.x;
        unsigned word1 = pp ? selw_r.w : selw_r.y;
        unsigned wsel0 = (word0 >> (lg2 * 16)) & 0xFFFFu;
        unsigned wsel1 = (word1 >> (lg2 * 16)) & 0xFFFFu;
        unsigned msk0 = (mt & 0x8000) ? 0xFFFFu : wsel0;
        unsigned msk1 = (mt & 0x8000) ? 0xFFFFu : wsel1;
        bool gl = (av < 512) && (((av >> 2) & 1) == lg2);
        int tr0 = (gl && (av >> 5) == pt0) ? ((av & 3) | (((av >> 3) & 3) << 2)) : -1;
        int tr1 = (gl && (av >> 5) == pt1) ? ((av & 3) | (((av >> 3) & 3) << 2)) : -1;
        float cv0 = 0.f, cv1 = 0.f;
#pragma unroll
        for (int r = 0; r < 16; ++r){
          float v0 = ((msk0 >> r) & 1u) ? NEG_INF : a0[r];
          float v1 = ((msk1 >> r) & 1u) ? NEG_INF : a1[r];
          sum += __builtin_amdgcn_exp2f(v0);
          sum += __builtin_amdgcn_exp2f(v1);
          if (r == tr0) cv0 = a0[r];
          if (r == tr1) cv1 = a1[r];
        }
        if (tr0 >= 0) chosen16[ln5] = f2bf(cv0);   // logit*log2e incl bias
        if (tr1 >= 0) chosen16[ln5] = f2bf(cv1);
      }
      sum += __shfl_xor(sum, 32);
      if (lg2 == 0) atomicAdd(&predsum[ln5], sum);
      // ---- commit this step's selection into the register mask ----
      if ((mt & A_NEW) && ((av >> 7) == wave)){
        int w2 = (av >> 5) & 3;
        unsigned bit = 1u << ((((av >> 2) & 1) << 4) | (av & 3) | (((av >> 3) & 3) << 2));
        if (w2 == 0) selw_r.x |= bit;
        else if (w2 == 1) selw_r.y |= bit;
        else if (w2 == 2) selw_r.z |= bit;
        else selw_r.w |= bit;
      }
    }
    __syncthreads();
  } // step loop

  // final step's finalize (t = 16)
  if (tid < 32){
    int s = tid;
    int m = amask[16][s];
    int av = m & 1023;
    int k = m >> 11;
    float stop = (k == 0) ? NEG_INF : stopp[s] + stopbias;
    float tot = __expf(stop) + predsum[s];
    float lse = __logf(tot);
    if (av != 1023){
      float ch;
      if (av == 512) ch = stop;
      else {
        bool mskd = !(m & A_NEW) || (k >= 16);
        ch = mskd ? NEG_INF : bf2f(chosen16[s]) * LN2;
      }
      logpf += ch - lse;
    }
    out[base + tid] = logpf;
  }
}

extern "C" void kernel_launch(void* const* d_in, const int* in_sizes, int n_in,
                              void* d_out, int out_size, void* d_ws, size_t ws_size,
                              hipStream_t stream)
{
  const int*   actions = (const int*)d_in[0];
  const float* rp  = (const float*)d_in[1];
  const float* W1  = (const float*)d_in[2];
  const float* b1  = (const float*)d_in[3];
  const float* W2  = (const float*)d_in[4];
  const float* b2  = (const float*)d_in[5];
  const float* Wh  = (const float*)d_in[6];
  const float* bh  = (const float*)d_in[7];
  float* out = (float*)d_out;

  unsigned short* w2f = (unsigned short*)d_ws;          // 65536  bf16 (128 KB)
  unsigned short* whf = w2f + 65536;                    // 131072 bf16 (256 KB)
  float* whstop = (float*)(whf + 131072);               // 256 f32

  prep_kernel<<<97, 256, 0, stream>>>(W2, Wh, w2f, whf, whstop);
  gfn_kernel<<<2048, 256, 0, stream>>>(actions, rp, W1, b1, b2, bh, w2f, whf, whstop, out);
}

// Round 19
// 572.126 us; speedup vs baseline: 1.0915x; 1.0915x over previous
//
#include <hip/hip_runtime.h>

// SubsetGFlowNetTB: 17-step GFlowNet trajectory-balance forward.
// R19 = R17 restored (proven 575us best; R18's 1-step/5-block variant paid
// 2x whf L2 traffic per sample-step -> 624us, closing the occupancy axis:
// R18(20w,1-step) < R15/R17(16w,2-step) > R13(12w)) + s_setprio(1) around
// the three MFMA inner loops (T5: pays when co-resident blocks are at
// different phases, which 4 independent blocks/CU gives us; no reg change).

#define NEG_INF (-1000000000.0f)
#define LOG2E 1.4426950408889634f
#define LN2   0.6931471805599453f

// amask ushort: [9:0] action (1023 = dead), [10] new, [15:11] kcnt (k>=16 <=> bit15)
#define A_NEW  0x400

// h LDS layout constants
#define HST 1040            // bytes per ktg block (65 rows * 16B)
#define HKT 2080            // kt stride = 2*HST

typedef short bf16x8 __attribute__((ext_vector_type(8)));
typedef float f32x16 __attribute__((ext_vector_type(16)));

__device__ __forceinline__ unsigned short f2bf(float x){
  unsigned int u = __float_as_uint(x);
  u = (u + 0x7FFFu + ((u >> 16) & 1u)) >> 16;   // RNE
  return (unsigned short)u;
}
__device__ __forceinline__ float bf2f(unsigned short h){
  return __uint_as_float(((unsigned int)h) << 16);
}
__device__ __forceinline__ unsigned int cvt_pk_bf16(float lo, float hi){
  unsigned int r;
  asm("v_cvt_pk_bf16_f32 %0, %1, %2" : "=v"(r) : "v"(lo), "v"(hi));
  return r;
}
__device__ __forceinline__ float4 ld4bf(const unsigned short* p){
  ushort4 u = *(const ushort4*)p;
  return make_float4(bf2f(u.x), bf2f(u.y), bf2f(u.z), bf2f(u.w));
}

// ---------------------------------------------------------------------------
// Prep: W2 (256x256 f32), Wh (256x513 f32) -> bf16 MFMA fragments.
// Layout: fragment tile index = ntg*16 + kt (kt fastest, 1024B kt-stride).
// Lane l of tile (ntg,kt) holds M[kt*16+(l>>5)*8+i][ntg*32+(l&31)].
// whf PRE-SCALED by log2(e).
// ---------------------------------------------------------------------------
__global__ void prep_kernel(const float* __restrict__ W2, const float* __restrict__ Wh,
                            unsigned short* __restrict__ w2f, unsigned short* __restrict__ whf,
                            float* __restrict__ whstop){
  int id = blockIdx.x * 256 + threadIdx.x;
  if (id < 8192){                       // W2 fragments: tile = ntg*16 + kt
    int lane = id & 63; int tile = id >> 6;
    int ntg = tile >> 4, kt = tile & 15;
    int col = ntg * 32 + (lane & 31);
    int k0  = kt * 16 + (lane >> 5) * 8;
    unsigned int u[4];
#pragma unroll
    for (int p = 0; p < 4; ++p){
      unsigned short lo = f2bf(W2[(k0 + 2*p    ) * 256 + col]);
      unsigned short hi = f2bf(W2[(k0 + 2*p + 1) * 256 + col]);
      u[p] = (unsigned int)lo | ((unsigned int)hi << 16);
    }
    *(uint4*)(w2f + (size_t)id * 8) = make_uint4(u[0], u[1], u[2], u[3]);
  } else if (id < 24576){               // Wh fragments: tile = pt*16 + kt, x log2e
    int id2 = id - 8192;
    int lane = id2 & 63; int tile = id2 >> 6;
    int pt = tile >> 4, kt = tile & 15;
    int col = pt * 32 + (lane & 31);
    int k0  = kt * 16 + (lane >> 5) * 8;
    unsigned int u[4];
#pragma unroll
    for (int p = 0; p < 4; ++p){
      unsigned short lo = f2bf(Wh[(k0 + 2*p    ) * 513 + col] * LOG2E);
      unsigned short hi = f2bf(Wh[(k0 + 2*p + 1) * 513 + col] * LOG2E);
      u[p] = (unsigned int)lo | ((unsigned int)hi << 16);
    }
    *(uint4*)(whf + (size_t)id2 * 8) = make_uint4(u[0], u[1], u[2], u[3]);
  } else if (id < 24832){               // stop column, f32, unscaled
    int k = id - 24576;
    whstop[k] = Wh[k * 513 + 512];
  }
}

// ---------------------------------------------------------------------------
// Fused kernel: 256 threads (4 waves) own 32 samples, 9 chunks x 2 steps.
// h in fragment-native layout h[32 ktg][65-row-pad][8 shorts]; rows 0-31 =
// step t, 32-63 = t+1; h1 then h2 per 32-row pass.
// ---------------------------------------------------------------------------
__launch_bounds__(256, 4)
__global__ void gfn_kernel(const int* __restrict__ actions, const float* __restrict__ rp,
                           const float* __restrict__ W1, const float* __restrict__ b1,
                           const float* __restrict__ b2, const float* __restrict__ bh,
                           const unsigned short* __restrict__ w2f,
                           const unsigned short* __restrict__ whf,
                           const float* __restrict__ whstop,
                           float* __restrict__ out)
{
  __shared__ alignas(16) char h[32 * HST];              // 33280 (h1, then h2)
  __shared__ alignas(16) unsigned short c16[1024];      // 2048: ck/ct/cr/cb bf16
  __shared__ alignas(16) float bhl2[512];               // 2048: bh*log2e f32 frag order
  __shared__ alignas(16) float b2s[256];                // 1024 f32
  __shared__ alignas(16) unsigned short whst_h[256];    // 512 stop col bf16
  __shared__ alignas(16) unsigned short amask[18][32];  // 1152
  __shared__ alignas(16) float predsum[64];             // 256 softmax partials
  __shared__ alignas(16) float stopp[64];               // 256 stop partials
  __shared__ alignas(16) unsigned short chosen16[64];   // 128  => 40704 total

  const int tid  = threadIdx.x;
  const int wave = tid >> 6;            // 0..3
  const int lane = tid & 63;
  const int ln5  = lane & 31;
  const int lg2  = lane >> 5;
  const int base = blockIdx.x * 32;

  // ---- init ----
  for (int i = tid; i < 1024; i += 256){
    int rrow = i >> 8, f = i & 255;
    float v = (rrow < 3) ? W1[(512 + rrow) * 256 + f] : b1[f];
    c16[i] = f2bf(v);
  }
  b2s[tid] = b2[tid];
  whst_h[tid] = f2bf(whstop[tid]);
  for (int i = tid; i < 512; i += 256){
    int pt = i >> 5, l2 = (i >> 4) & 1, r = i & 15;
    int col = pt * 32 + (r & 3) + 8 * (r >> 2) + 4 * l2;
    bhl2[i] = bh[col] * LOG2E;
  }
  const float stopbias = bh[512];
  if (tid < 64){ stopp[tid] = 0.f; predsum[tid] = 0.f; }
  int* acts = (int*)h;                  // stage actions in h scratch
  for (int i = tid; i < 544; i += 256) acts[i] = actions[base * 17 + i];
  float logpf = 0.f;                    // valid for tid<32 (sample tid)
  // selection mask in registers: wave w owns pt-words w*4..w*4+3 for its
  // sample ln5 (maintained redundantly by both half-waves)
  uint4 selw_r = make_uint4(0u, 0u, 0u, 0u);
  __syncthreads();

  // ---- state precompute: O(17^2) scan per sample; no GEMM dependency ----
  if (tid < 32){
    int s = tid, k = 0;
    for (int t = 0; t < 17; ++t){
      int a = acts[s * 17 + t];
      bool alive = (a >= 0);
      bool isnew = alive && (a < 512);
      if (isnew){
        for (int u = 0; u < t; ++u) if (acts[s * 17 + u] == a){ isnew = false; break; }
      }
      int av = alive ? a : 1023;
      amask[t][s] = (unsigned short)(av | (isnew ? A_NEW : 0) | (k << 11));
      if (isnew) ++k;
    }
    amask[17][s] = (unsigned short)(1023 | (k << 11));   // dummy step
  }
  // packed layer-1 running sum: Spk[2*s8+{0,1}] = bf16x2 of feats {0,1},{2,3}
  unsigned int Spk[16];
#pragma unroll
  for (int j = 0; j < 16; ++j) Spk[j] = 0u;
  __syncthreads();

  // fragment-layout base addresses (all loop-invariant, 32-bit)
  const int aw_base = (lane >> 1) * HST + (lane & 1) * 8 + wave * 128; // A writes
  const int br_base = lg2 * HST;                                      // B reads
  const int bw_base = wave * 8 * HST + lg2 * 8;                       // B writes
  const int cr_base = lg2 * HST + ln5 * 16;                           // C reads
  const int rpu = __builtin_amdgcn_readfirstlane(base + wave * 8);    // uniform rp index
  // weight-fragment per-lane bases (32-bit offsets; kt-stride 512 shorts)
  const unsigned lane8 = (unsigned)lane * 8u;
  const unsigned short* w2p0 = w2f + (unsigned)(wave * 2    ) * 8192u + lane8;
  const unsigned short* w2p1 = w2f + (unsigned)(wave * 2 + 1) * 8192u + lane8;

#pragma unroll 1
  for (int c = 0; c < 9; ++c){
    const int t = c * 2;

    // ---- Phase A: h1 rows for steps t and t+1; incremental t+1 ----
    {
      const float4 ck4 = ld4bf(&c16[lane * 4]);
      const float4 ct4 = ld4bf(&c16[256 + lane * 4]);
      const float4 cr4 = ld4bf(&c16[512 + lane * 4]);
      const float4 cb4 = ld4bf(&c16[768 + lane * 4]);
      float tf = (float)t;
      float c00 = cb4.x + tf * ct4.x, c01 = cb4.y + tf * ct4.y;
      float c02 = cb4.z + tf * ct4.z, c03 = cb4.w + tf * ct4.w;
#pragma unroll
      for (int s8 = 0; s8 < 8; ++s8){
        int s = wave * 8 + s8;
        float rv = rp[rpu + s8];                 // scalar load
        int m0 = amask[t][s];
        int m1 = amask[t + 1][s];
        unsigned int pk0 = Spk[s8 * 2], pk1 = Spk[s8 * 2 + 1];
        float S0 = __uint_as_float(pk0 << 16);
        float S1 = __uint_as_float(pk0 & 0xFFFF0000u);
        float S2 = __uint_as_float(pk1 << 16);
        float S3 = __uint_as_float(pk1 & 0xFFFF0000u);
        float kf = (float)(m0 >> 11);
        float v0 = S0 + kf * ck4.x + rv * cr4.x + c00;
        float v1 = S1 + kf * ck4.y + rv * cr4.y + c01;
        float v2 = S2 + kf * ck4.z + rv * cr4.z + c02;
        float v3 = S3 + kf * ck4.w + rv * cr4.w + c03;
        *(uint2*)(h + aw_base + s8 * 16) =
            make_uint2(cvt_pk_bf16(fmaxf(v0,0.f), fmaxf(v1,0.f)),
                       cvt_pk_bf16(fmaxf(v2,0.f), fmaxf(v3,0.f)));
        float d0 = ct4.x, d1 = ct4.y, d2 = ct4.z, d3 = ct4.w;
        if (m0 & A_NEW){
          int a = m0 & 1023;
          float4 w = *(const float4*)(W1 + (size_t)a * 256 + lane * 4);
          S0 += w.x; S1 += w.y; S2 += w.z; S3 += w.w;
          d0 += w.x + ck4.x; d1 += w.y + ck4.y; d2 += w.z + ck4.z; d3 += w.w + ck4.w;
        }
        v0 += d0; v1 += d1; v2 += d2; v3 += d3;
        *(uint2*)(h + aw_base + 512 + s8 * 16) =
            make_uint2(cvt_pk_bf16(fmaxf(v0,0.f), fmaxf(v1,0.f)),
                       cvt_pk_bf16(fmaxf(v2,0.f), fmaxf(v3,0.f)));
        if (m1 & A_NEW){
          int a = m1 & 1023;
          float4 w = *(const float4*)(W1 + (size_t)a * 256 + lane * 4);
          S0 += w.x; S1 += w.y; S2 += w.z; S3 += w.w;
        }
        if ((m0 | m1) & A_NEW){
          Spk[s8 * 2]     = cvt_pk_bf16(S0, S1);
          Spk[s8 * 2 + 1] = cvt_pk_bf16(S2, S3);
        }
      }
    }
    __syncthreads();

    // ---- deferred finalize of previous chunk (tid<32; overlaps B's MFMA on
    //      other waves; resets complete before B's mid-barrier, and B's stopp
    //      atomics happen only after that barrier) ----
    if (c > 0 && tid < 32){
      int tprev = t - 2;
      int s = tid;
      int m0 = amask[tprev][s];
      int m1 = amask[tprev + 1][s];
      int av0 = m0 & 1023, av1 = m1 & 1023;
      int k0 = m0 >> 11, k1 = m1 >> 11;
      float stop0 = (k0 == 0) ? NEG_INF : stopp[s] + stopbias;
      float stop1 = (k1 == 0) ? NEG_INF : stopp[32 + s] + stopbias;
      {
        float tot = __expf(stop0) + predsum[s];
        float lse = __logf(tot);
        if (av0 != 1023){
          float ch;
          if (av0 == 512) ch = stop0;
          else {
            bool mskd = !(m0 & A_NEW) || (k0 >= 16);
            ch = mskd ? NEG_INF : bf2f(chosen16[s]) * LN2;
          }
          logpf += ch - lse;
        }
      }
      {
        float tot = __expf(stop1) + predsum[32 + s];
        float lse = __logf(tot);
        if (av1 != 1023){
          float ch;
          if (av1 == 512) ch = stop1;
          else {
            bool mskd = !(m1 & A_NEW) || (k1 >= 16);
            ch = mskd ? NEG_INF : bf2f(chosen16[32 + s]) * LN2;
          }
          logpf += ch - lse;
        }
      }
      stopp[s] = 0.f; stopp[32 + s] = 0.f;
      predsum[s] = 0.f; predsum[32 + s] = 0.f;
    }

    // ---- Phase B (swapped): D'[feat][row]; 2 sequential passes over the
    //      SINGLE h buffer. Stop-dot folded into the epilogue.
#pragma unroll 1
    for (int q = 0; q < 2; ++q){
      const int rr = q * 32 + ln5;
      const int brq = br_base + rr * 16;
      f32x16 aB0, aB1;
#pragma unroll
      for (int i = 0; i < 16; ++i){ aB0[i] = 0.f; aB1[i] = 0.f; }
      __builtin_amdgcn_s_setprio(1);
#pragma unroll 4
      for (int kt = 0; kt < 16; ++kt){
        bf16x8 sf = *(const bf16x8*)(h + brq + kt * HKT);
        bf16x8 w0 = *(const bf16x8*)(w2p0 + (unsigned)(kt * 512));
        bf16x8 w1 = *(const bf16x8*)(w2p1 + (unsigned)(kt * 512));
        aB0 = __builtin_amdgcn_mfma_f32_32x32x16_bf16(w0, sf, aB0, 0, 0, 0);
        aB1 = __builtin_amdgcn_mfma_f32_32x32x16_bf16(w1, sf, aB1, 0, 0, 0);
      }
      __builtin_amdgcn_s_setprio(0);
      __syncthreads();   // all waves done reading h1 rows [32q,+32)
      const int bwq = bw_base + rr * 16;
      float sp = 0.f;
#pragma unroll
      for (int g = 0; g < 4; ++g){
        int f0 = wave * 64 + g * 8 + lg2 * 4;
        int f1 = f0 + 32;
        float4 bb0 = *(const float4*)&b2s[f0];
        float4 bb1 = *(const float4*)&b2s[f1];
        float4 ws0 = ld4bf(&whst_h[f0]);
        float4 ws1 = ld4bf(&whst_h[f1]);
        {
          float v0 = fmaxf(aB0[g*4+0] + bb0.x, 0.f), v1 = fmaxf(aB0[g*4+1] + bb0.y, 0.f);
          float v2 = fmaxf(aB0[g*4+2] + bb0.z, 0.f), v3 = fmaxf(aB0[g*4+3] + bb0.w, 0.f);
          sp += v0 * ws0.x + v1 * ws0.y + v2 * ws0.z + v3 * ws0.w;
          *(uint2*)(h + bwq + g * HST) = make_uint2(cvt_pk_bf16(v0, v1), cvt_pk_bf16(v2, v3));
        }
        {
          float v0 = fmaxf(aB1[g*4+0] + bb1.x, 0.f), v1 = fmaxf(aB1[g*4+1] + bb1.y, 0.f);
          float v2 = fmaxf(aB1[g*4+2] + bb1.z, 0.f), v3 = fmaxf(aB1[g*4+3] + bb1.w, 0.f);
          sp += v0 * ws1.x + v1 * ws1.y + v2 * ws1.z + v3 * ws1.w;
          *(uint2*)(h + bwq + (g + 4) * HST) = make_uint2(cvt_pk_bf16(v0, v1), cvt_pk_bf16(v2, v3));
        }
      }
      sp += __shfl_xor(sp, 32);
      if (lg2 == 0) atomicAdd(&stopp[rr], sp);
    }
    __syncthreads();   // h2 fully written, stopp complete

    // ---- Phase C (swapped): lane owns sample ln5 (both steps); 4 passes,
    //      2 accs (rt0/rt1) sharing one whf fetch; acc init = bias*log2e.
    {
      int mt  = amask[t][ln5];
      int mt1 = amask[t + 1][ln5];
      int av0 = mt & 1023, av1 = mt1 & 1023;
      int pa = (mt & A_NEW) ? av0 : -1;     // patch col for step t+1 mask
      float sum0 = 0.f, sum1 = 0.f;
#pragma unroll 1
      for (int p = 0; p < 4; ++p){
        int pt = wave * 4 + p;
        const unsigned short* wp = whf + (unsigned)pt * 8192u + lane8;
        const float* bi = &bhl2[pt * 32 + lg2 * 16];
        float4 b0_ = *(const float4*)(bi);
        float4 b1_ = *(const float4*)(bi + 4);
        float4 b2_ = *(const float4*)(bi + 8);
        float4 b3_ = *(const float4*)(bi + 12);
        f32x16 a0, a1;
        a0[0]=b0_.x; a0[1]=b0_.y; a0[2]=b0_.z; a0[3]=b0_.w;
        a0[4]=b1_.x; a0[5]=b1_.y; a0[6]=b1_.z; a0[7]=b1_.w;
        a0[8]=b2_.x; a0[9]=b2_.y; a0[10]=b2_.z; a0[11]=b2_.w;
        a0[12]=b3_.x; a0[13]=b3_.y; a0[14]=b3_.z; a0[15]=b3_.w;
        a1 = a0;
        __builtin_amdgcn_s_setprio(1);
#pragma unroll 4
        for (int kt = 0; kt < 16; ++kt){
          bf16x8 f0 = *(const bf16x8*)(h + cr_base + kt * HKT);
          bf16x8 f1 = *(const bf16x8*)(h + cr_base + 512 + kt * HKT);
          bf16x8 w = *(const bf16x8*)(wp + (unsigned)(kt * 512));
          a0 = __builtin_amdgcn_mfma_f32_32x32x16_bf16(w, f0, a0, 0, 0, 0);
          a1 = __builtin_amdgcn_mfma_f32_32x32x16_bf16(w, f1, a1, 0, 0, 0);
        }
        __builtin_amdgcn_s_setprio(0);
        // selection word for this pt from registers (p runtime -> cndmask)
        unsigned wlo = (p & 1) ? selw_r.y : selw_r.x;
        unsigned whi = (p & 1) ? selw_r.w : selw_r.z;
        unsigned word = (p & 2) ? whi : wlo;
        unsigned wsel = (word >> (lg2 * 16)) & 0xFFFFu;
        unsigned msk0 = (mt  & 0x8000) ? 0xFFFFu : wsel;
        unsigned msk1 = (mt1 & 0x8000) ? 0xFFFFu : wsel;
        if (pa >= 0 && (pa >> 5) == pt && (((pa >> 2) & 1) == lg2))
          msk1 |= 1u << ((pa & 3) | (((pa >> 3) & 3) << 2));
        int tr0 = (av0 < 512 && (av0 >> 5) == pt && (((av0 >> 2) & 1) == lg2))
                  ? ((av0 & 3) | (((av0 >> 3) & 3) << 2)) : -1;
        int tr1 = (av1 < 512 && (av1 >> 5) == pt && (((av1 >> 2) & 1) == lg2))
                  ? ((av1 & 3) | (((av1 >> 3) & 3) << 2)) : -1;
        float cv0 = 0.f, cv1 = 0.f;
#pragma unroll
        for (int r = 0; r < 16; ++r){
          float v0 = ((msk0 >> r) & 1u) ? NEG_INF : a0[r];
          float v1 = ((msk1 >> r) & 1u) ? NEG_INF : a1[r];
          sum0 += __builtin_amdgcn_exp2f(v0);
          sum1 += __builtin_amdgcn_exp2f(v1);
          if (r == tr0) cv0 = a0[r];
          if (r == tr1) cv1 = a1[r];
        }
        if (tr0 >= 0) chosen16[ln5]      = f2bf(cv0);   // logit*log2e incl bias
        if (tr1 >= 0) chosen16[32 + ln5] = f2bf(cv1);
      }
      sum0 += __shfl_xor(sum0, 32);
      sum1 += __shfl_xor(sum1, 32);
      if (lg2 == 0){
        atomicAdd(&predsum[ln5], sum0);
        atomicAdd(&predsum[32 + ln5], sum1);
      }
      // ---- commit this chunk's selections into the register mask ----
#pragma unroll
      for (int e = 0; e < 2; ++e){
        int m = e ? mt1 : mt;
        if ((m & A_NEW) && (((m & 1023) >> 7) == wave)){
          int av = m & 1023;
          int w2 = (av >> 5) & 3;
          unsigned bit = 1u << ((((av >> 2) & 1) << 4) | (av & 3) | (((av >> 3) & 3) << 2));
          if (w2 == 0) selw_r.x |= bit;
          else if (w2 == 1) selw_r.y |= bit;
          else if (w2 == 2) selw_r.z |= bit;
          else selw_r.w |= bit;
        }
      }
    }
    __syncthreads();
  } // chunk loop

  // final chunk's finalize (steps 16/17)
  if (tid < 32){
    int s = tid;
    int m0 = amask[16][s];
    int m1 = amask[17][s];
    int av0 = m0 & 1023, av1 = m1 & 1023;
    int k0 = m0 >> 11, k1 = m1 >> 11;
    float stop0 = (k0 == 0) ? NEG_INF : stopp[s] + stopbias;
    float stop1 = (k1 == 0) ? NEG_INF : stopp[32 + s] + stopbias;
    {
      float tot = __expf(stop0) + predsum[s];
      float lse = __logf(tot);
      if (av0 != 1023){
        float ch;
        if (av0 == 512) ch = stop0;
        else {
          bool mskd = !(m0 & A_NEW) || (k0 >= 16);
          ch = mskd ? NEG_INF : bf2f(chosen16[s]) * LN2;
        }
        logpf += ch - lse;
      }
    }
    {
      float tot = __expf(stop1) + predsum[32 + s];
      float lse = __logf(tot);
      if (av1 != 1023){
        float ch;
        if (av1 == 512) ch = stop1;
        else {
          bool mskd = !(m1 & A_NEW) || (k1 >= 16);
          ch = mskd ? NEG_INF : bf2f(chosen16[32 + s]) * LN2;
        }
        logpf += ch - lse;
      }
    }
    out[base + tid] = logpf;
  }
}

extern "C" void kernel_launch(void* const* d_in, const int* in_sizes, int n_in,
                              void* d_out, int out_size, void* d_ws, size_t ws_size,
                              hipStream_t stream)
{
  const int*   actions = (const int*)d_in[0];
  const float* rp  = (const float*)d_in[1];
  const float* W1  = (const float*)d_in[2];
  const float* b1  = (const float*)d_in[3];
  const float* W2  = (const float*)d_in[4];
  const float* b2  = (const float*)d_in[5];
  const float* Wh  = (const float*)d_in[6];
  const float* bh  = (const float*)d_in[7];
  float* out = (float*)d_out;

  unsigned short* w2f = (unsigned short*)d_ws;          // 65536  bf16 (128 KB)
  unsigned short* whf = w2f + 65536;                    // 131072 bf16 (256 KB)
  float* whstop = (float*)(whf + 131072);               // 256 f32

  prep_kernel<<<97, 256, 0, stream>>>(W2, Wh, w2f, whf, whstop);
  gfn_kernel<<<2048, 256, 0, stream>>>(actions, rp, W1, b1, b2, bh, w2f, whf, whstop, out);
}